// Round 8
// baseline (451.817 us; speedup 1.0000x reference)
//
#include <hip/hip_runtime.h>

#define H      128
#define OBSROW 141
#define GPB    16     // graphs per block (MFMA M dimension)
#define NT     1024   // 16 waves = 8 o-tiles x 2 node-halves

typedef __bf16 bf16x8 __attribute__((ext_vector_type(8)));
typedef float  f32x4  __attribute__((ext_vector_type(4)));

__device__ __forceinline__ float eluf(float v) {
    return v > 0.0f ? v : (__expf(v) - 1.0f);
}
__device__ __forceinline__ unsigned int pk2(float a, float b) {
    const unsigned short lo = __builtin_bit_cast(unsigned short, (__bf16)a);
    const unsigned short hi = __builtin_bit_cast(unsigned short, (__bf16)b);
    return (unsigned)lo | ((unsigned)hi << 16);
}
__device__ __forceinline__ float upk(unsigned int p, int e) {
    return (float)__builtin_bit_cast(__bf16, (unsigned short)(e ? (p >> 16) : p));
}
__device__ __forceinline__ f32x4 yv(const unsigned int* p) {
    f32x4 r; r[0] = upk(p[0],0); r[1] = upk(p[0],1); r[2] = upk(p[1],0); r[3] = upk(p[1],1);
    return r;
}

// ws (bf16 elems): [0)Wrel 3*16384 | [49152)Wroot 3*16384 | [98304)We_b pad[128][64] | [106496)We_j pad[128][32]
#define WS_ROOT 49152
#define WS_EB   98304
#define WS_EJ   106496
#define WS_TOT  110592

__global__ void convert_weights(const float* __restrict__ Wr, const float* __restrict__ Wo,
                                const float* __restrict__ Web, const float* __restrict__ Wej,
                                __bf16* __restrict__ ws) {
    const int i = blockIdx.x * 256 + threadIdx.x;
    if (i < WS_ROOT) {
        ws[i] = (__bf16)Wr[i];
    } else if (i < WS_EB) {
        ws[i] = (__bf16)Wo[i - WS_ROOT];
    } else if (i < WS_EJ) {
        const int j = i - WS_EB, o = j >> 6, f = j & 63;
        ws[i] = (__bf16)(f < 33 ? Web[o*33 + f] : 0.0f);
    } else if (i < WS_TOT) {
        const int j = i - WS_EJ, o = j >> 5, f = j & 31;
        ws[i] = (__bf16)(f < 9 ? Wej[o*9 + f] : 0.0f);
    }
}

// X layout: [node 13][hc=h/8 16][graph 16][hi 8]  (bf16) -> A-frag = 16B contiguous
#define XIDX(n,hc,g,hi) (((((n)*16 + (hc))*16 + (g))*8) + (hi))
// cross-Yrel tiles (f32 C-layout): t 0..2 = nodes {0,7,10}
#define YC(t,j,ln) ((((t)*8 + (j))*64 + (ln))*4)

__launch_bounds__(NT, 8)   // 8 waves/EU -> 64-reg cap; lean phases keep demand ~60
__global__ void gnn_fused(const float* __restrict__ obs,
                          const float* __restrict__ be_b, const float* __restrict__ be_j,
                          const float* __restrict__ b_rel,
                          const float* __restrict__ W_dec, const float* __restrict__ b_dec,
                          const __bf16* __restrict__ wsb,
                          float* __restrict__ out, int B)
{
    __shared__ __align__(16) unsigned short Xs[13*2048];   // 53248 B (single buffer)
    __shared__ __align__(16) float Yc[3*8*64*4];           // 24576 B (also obs staging)

    const int tid  = threadIdx.x;
    const int wave = tid >> 6;     // 0..15
    const int half = wave >> 3;    // 0 -> nodes 0..6, 1 -> nodes 7..12
    const int jt   = wave & 7;     // o-tile
    const int lane = tid & 63;
    const int q    = lane >> 4;    // quad 0..3
    const int c    = lane & 15;    // col-in-tile / graph-in-chunk
    const int g0   = blockIdx.x * GPB;
    const int o    = jt*16 + c;

    unsigned short* Fs = (unsigned short*)Yc;   // staging view (14336 B used)

    // ---------------- stage obs features ----------------
    // joints at Fs[jj*512 + fc*128 + g*8 + hi] (jj 0..11, f = fc*8+hi, f<9 valid)
    for (int s = tid; s < 6144; s += NT) {
        const int jj = s >> 9, rem = s & 511;
        const int fc = rem >> 7, g = (rem >> 3) & 15, hi = rem & 7;
        const int f = fc*8 + hi;
        float v = 0.0f;
        if (f < 9 && (g0 + g) < B)
            v = obs[(g0+g)*OBSROW + (f/3)*47 + 9 + (f%3)*12 + jj];
        *(__bf16*)&Fs[s] = (__bf16)v;
    }
    // base at Fs[6144 + fc*128 + g*8 + hi] (f = fc*8+hi, f<33 valid, K padded to 64)
    {
        const int s = tid;
        const int fc = s >> 7, rem = s & 127, g = rem >> 3, hi = rem & 7;
        const int f = fc*8 + hi;
        float v = 0.0f;
        if (f < 33 && (g0 + g) < B) {
            const int tt = f / 11, i2 = f % 11;   // BASE_IDX[i] = i<9 ? i : 36+i
            v = obs[(g0+g)*OBSROW + tt*47 + (i2 < 9 ? i2 : 36 + i2)];
        }
        *(__bf16*)&Fs[6144 + s] = (__bf16)v;
    }
    __syncthreads();

    // ---------------- encoders ----------------
    if (half == 0) {   // node 0 (base), K=64 -> 2 MFMAs
        const bf16x8 u0 = *(const bf16x8*)(wsb + WS_EB + o*64 + q*8);
        const bf16x8 u1 = *(const bf16x8*)(wsb + WS_EB + o*64 + 32 + q*8);
        const bf16x8 a0 = *(const bf16x8*)&Fs[6144 + q*128 + c*8];
        const bf16x8 a1 = *(const bf16x8*)&Fs[6144 + 512 + q*128 + c*8];
        f32x4 acc = {0.f,0.f,0.f,0.f};
        acc = __builtin_amdgcn_mfma_f32_16x16x32_bf16(a0, u0, acc, 0,0,0);
        acc = __builtin_amdgcn_mfma_f32_16x16x32_bf16(a1, u1, acc, 0,0,0);
        const float bias = be_b[o];
        #pragma unroll
        for (int r = 0; r < 4; r++)
            *(__bf16*)&Xs[XIDX(0, jt*2 + (c>>3), q*4 + r, c & 7)] = (__bf16)eluf(acc[r] + bias);
    }
    {   // joints: each wave does 6 of them for its o-tile, K=32 -> 1 MFMA each
        const bf16x8 uj = *(const bf16x8*)(wsb + WS_EJ + o*32 + q*8);
        const float bias = be_j[o];
        #pragma unroll
        for (int t2 = 0; t2 < 6; t2++) {
            const int jj = half*6 + t2;
            const bf16x8 a = *(const bf16x8*)&Fs[jj*512 + q*128 + c*8];
            f32x4 acc = {0.f,0.f,0.f,0.f};
            acc = __builtin_amdgcn_mfma_f32_16x16x32_bf16(a, uj, acc, 0,0,0);
            #pragma unroll
            for (int r = 0; r < 4; r++)
                *(__bf16*)&Xs[XIDX(1+jj, jt*2 + (c>>3), q*4 + r, c & 7)] = (__bf16)eluf(acc[r] + bias);
        }
    }
    __syncthreads();

    // ---------------- 3 GraphConv layers (3 barriers each, 2 blocks/CU overlap) ----------------
    const unsigned short* xr = Xs + q*128 + c*8;   // A-frag(n,k) at xr + n*2048 + k*512
    const int n0  = half*7;
    const int cnt = 7 - half;
    #pragma unroll 1
    for (int l = 0; l < 3; l++) {
        unsigned int yp[7][2];     // own-half Yrel tiles, packed bf16 (14 regs)
        #define MFMA4(dst, n, bw)                                                     \
            { f32x4 acc_ = {0.f,0.f,0.f,0.f};                                         \
              _Pragma("unroll")                                                       \
              for (int k = 0; k < 4; k++)                                             \
                  acc_ = __builtin_amdgcn_mfma_f32_16x16x32_bf16(                     \
                      *(const bf16x8*)(xr + (n)*2048 + k*512), bw[k], acc_, 0,0,0);   \
              dst = acc_; }
        #define PK(i, y) { yp[i][0] = pk2(y[0], y[1]); yp[i][1] = pk2(y[2], y[3]); }

        // ---- phase R: rel MFMAs; cross tiles -> LDS (f32); own tiles -> packed regs
        {
            bf16x8 bw[4];
            #pragma unroll
            for (int k = 0; k < 4; k++)
                bw[k] = *(const bf16x8*)(wsb + l*16384 + o*128 + k*32 + q*8);
            f32x4 y;
            if (half == 0) {
                MFMA4(y, 0, bw); *(f32x4*)&Yc[YC(0, jt, lane)] = y; PK(0, y);
                MFMA4(y, 1, bw); PK(1, y);
                MFMA4(y, 2, bw); PK(2, y);
                MFMA4(y, 3, bw); PK(3, y);
                MFMA4(y, 4, bw); PK(4, y);
                MFMA4(y, 5, bw); PK(5, y);
                MFMA4(y, 6, bw); PK(6, y);
            } else {
                MFMA4(y, 7,  bw); *(f32x4*)&Yc[YC(1, jt, lane)] = y; PK(0, y);
                MFMA4(y, 10, bw); *(f32x4*)&Yc[YC(2, jt, lane)] = y; PK(3, y);
                MFMA4(y, 8,  bw); PK(1, y);
                MFMA4(y, 9,  bw); PK(2, y);
                MFMA4(y, 11, bw); PK(4, y);
                MFMA4(y, 12, bw); PK(5, y);
            }
        }
        __syncthreads();   // barrier 1: cross tiles visible

        // ---- phase O: acc = sum_src Yrel; acc += W_root·x[n]; elu -> packed stash
        unsigned int stash[7][2];
        {
            bf16x8 bw[4];
            #pragma unroll
            for (int k = 0; k < 4; k++)
                bw[k] = *(const bf16x8*)(wsb + WS_ROOT + l*16384 + o*128 + k*32 + q*8);
            const float bias = b_rel[l*H + o];
            #define FIN(i, n, SUMEXPR)                                                    \
                { f32x4 acc = (SUMEXPR);                                                  \
                  _Pragma("unroll")                                                       \
                  for (int k = 0; k < 4; k++)                                             \
                      acc = __builtin_amdgcn_mfma_f32_16x16x32_bf16(                      \
                          *(const bf16x8*)(xr + (n)*2048 + k*512), bw[k], acc, 0,0,0);    \
                  stash[i][0] = pk2(eluf(acc[0]+bias), eluf(acc[1]+bias));                \
                  stash[i][1] = pk2(eluf(acc[2]+bias), eluf(acc[3]+bias)); }
            if (half == 0) {
                const f32x4 y7  = *(const f32x4*)&Yc[YC(1, jt, lane)];
                const f32x4 y10 = *(const f32x4*)&Yc[YC(2, jt, lane)];
                FIN(0, 0, yv(yp[1]) + yv(yp[4]) + y7 + y10);
                FIN(1, 1, yv(yp[0]) + yv(yp[2]));
                FIN(2, 2, yv(yp[1]) + yv(yp[3]));
                FIN(3, 3, yv(yp[2]));
                FIN(4, 4, yv(yp[0]) + yv(yp[5]));
                FIN(5, 5, yv(yp[4]) + yv(yp[6]));
                FIN(6, 6, yv(yp[5]));
            } else {
                const f32x4 y0 = *(const f32x4*)&Yc[YC(0, jt, lane)];
                FIN(0, 7,  y0 + yv(yp[1]));
                FIN(1, 8,  yv(yp[0]) + yv(yp[2]));
                FIN(2, 9,  yv(yp[1]));
                FIN(3, 10, y0 + yv(yp[4]));
                FIN(4, 11, yv(yp[3]) + yv(yp[5]));
                FIN(5, 12, yv(yp[4]));
            }
            #undef FIN
        }
        __syncthreads();   // barrier 2: all X reads done

        // ---- write new X in place
        {
            const int hc = jt*2 + (c >> 3);
            const int hi = c & 7;
            #pragma unroll
            for (int idx = 0; idx < 7; idx++) {
                if (idx < cnt) {
                    const int n = n0 + idx;
                    Xs[XIDX(n, hc, q*4+0, hi)] = (unsigned short)(stash[idx][0]);
                    Xs[XIDX(n, hc, q*4+1, hi)] = (unsigned short)(stash[idx][0] >> 16);
                    Xs[XIDX(n, hc, q*4+2, hi)] = (unsigned short)(stash[idx][1]);
                    Xs[XIDX(n, hc, q*4+3, hi)] = (unsigned short)(stash[idx][1] >> 16);
                }
            }
        }
        __syncthreads();   // barrier 3: new X visible
        #undef MFMA4
        #undef PK
    }

    // ---------------- decoder: out[g][j] = x[j+1]·W_dec + b_dec ----------------
    if (wave < 12) {
        // decoder base: hc = q*4 + hq  ->  h = q*32 + hq*8 + hi (matches wd indexing)
        const unsigned short* xdec = Xs + q*512 + c*8;
        float wd[32];
        #pragma unroll
        for (int i4 = 0; i4 < 8; i4++) {
            const float4 wv = *(const float4*)&W_dec[q*32 + i4*4];
            wd[i4*4+0] = wv.x; wd[i4*4+1] = wv.y; wd[i4*4+2] = wv.z; wd[i4*4+3] = wv.w;
        }
        const float bd = b_dec[0];
        const int j = wave;                 // joint 0..11
        float s = 0.0f;
        #pragma unroll
        for (int hq = 0; hq < 4; hq++) {    // lane covers h = q*32 + hq*8 + hi
            const bf16x8 xv = *(const bf16x8*)(xdec + (j+1)*2048 + hq*128);
            #pragma unroll
            for (int hi2 = 0; hi2 < 8; hi2++)
                s += (float)xv[hi2] * wd[hq*8 + hi2];
        }
        s += __shfl_xor(s, 16);
        s += __shfl_xor(s, 32);
        if (q == 0 && (g0 + c) < B)
            out[(g0 + c)*12 + j] = s + bd;
    }
}

extern "C" void kernel_launch(void* const* d_in, const int* in_sizes, int n_in,
                              void* d_out, int out_size, void* d_ws, size_t ws_size,
                              hipStream_t stream) {
    const float* obs   = (const float*)d_in[0];
    const float* We_b  = (const float*)d_in[1];
    const float* be_b  = (const float*)d_in[2];
    const float* We_j  = (const float*)d_in[3];
    const float* be_j  = (const float*)d_in[4];
    const float* W_rel = (const float*)d_in[5];
    const float* W_root= (const float*)d_in[6];
    const float* b_rel = (const float*)d_in[7];
    const float* W_dec = (const float*)d_in[8];
    const float* b_dec = (const float*)d_in[9];
    // d_in[10]/d_in[11] (src/dst) are the fixed tree edges; adjacency is baked in.
    float* out = (float*)d_out;
    __bf16* wsb = (__bf16*)d_ws;   // 221 KB of bf16 weights

    const int B = in_sizes[0] / OBSROW;
    convert_weights<<<(WS_TOT + 255) / 256, 256, 0, stream>>>(W_rel, W_root, We_b, We_j, wsb);
    const int blocks = (B + GPB - 1) / GPB;
    gnn_fused<<<blocks, NT, 0, stream>>>(obs, be_b, be_j, b_rel, W_dec, b_dec,
                                         wsb, out, B);
}